// Round 3
// baseline (810.138 us; speedup 1.0000x reference)
//
#include <hip/hip_runtime.h>

// ---------------- problem constants ----------------
#define NN      50000      // nodes
#define NE      500000     // edges (before self loops)
#define NET     550000     // edges + self loops
#define IND     256        // input dim
#define HC      512        // heads*hidden
#define NH      4          // heads
#define NG      512        // graphs
#define NCLS    10

typedef __attribute__((ext_vector_type(8))) short bf16x8;
typedef __attribute__((ext_vector_type(4))) float f32x4;

// ---------------- bf16 split helpers (RNE) ----------------
__device__ __forceinline__ ushort f2bf(float x) {
    unsigned u = __float_as_uint(x);
    u += 0x7fffu + ((u >> 16) & 1u);
    return (ushort)(u >> 16);
}
__device__ __forceinline__ float bf2f(ushort h) {
    return __uint_as_float((unsigned)h << 16);
}

// async global->LDS, 16B per lane. dst must be wave-uniform base (+lane*16 by HW).
__device__ __forceinline__ void gload_lds16(const void* g, void* s) {
    __builtin_amdgcn_global_load_lds(
        (const __attribute__((address_space(1))) unsigned*)g,
        (__attribute__((address_space(3))) unsigned*)s, 16, 0, 0);
}

// ---------------- split-bf16 MFMA GEMM ----------------
// C[M,512] = (Ahi+Alo)[M,K] @ (Bhi+Blo)[K,512]  (minus Alo*Blo, ~2^-18)
// computed as 3 K-segments: (Ahi,Bhi), (Ahi,Blo), (Alo,Bhi).
__global__ __launch_bounds__(256) void k_gemm_mfma(
    const ushort* __restrict__ Ahi, const ushort* __restrict__ Alo,
    const ushort* __restrict__ BhiT, const ushort* __restrict__ BloT,
    float* __restrict__ C, int M, int K)
{
    __shared__ __align__(16) ushort As[128 * 64];
    __shared__ __align__(16) ushort Bs[128 * 64];

    const int tid = threadIdx.x;
    const int nwg = gridDim.x;
    const int orig = blockIdx.x;
    const int q = nwg >> 3, r = nwg & 7, xcd = orig & 7;
    const int wgid = (xcd < r ? xcd * (q + 1) : r * (q + 1) + (xcd - r) * q) + (orig >> 3);
    const int bm = (wgid >> 2) * 128;
    const int bn = (wgid & 3) * 128;

    const int l = tid & 63;
    const int w = tid >> 6;
    const int wm = (w >> 1) * 64, wn = (w & 1) * 64;
    const int fr = l & 15;
    const int fk = (l >> 4) * 8;

    f32x4 zero = {0.f, 0.f, 0.f, 0.f};
    f32x4 acc[4][4];
#pragma unroll
    for (int m = 0; m < 4; ++m)
#pragma unroll
        for (int n = 0; n < 4; ++n) acc[m][n] = zero;

    const int spseg = K >> 6;
    const int total = 3 * spseg;
    const int wbase = (tid & 0xC0) << 4;

    for (int ks = 0; ks < total; ++ks) {
        int seg = (ks >= spseg) + (ks >= 2 * spseg);
        int k0 = (ks - seg * spseg) << 6;
        const ushort* Ab = (seg == 2) ? Alo : Ahi;
        const ushort* Bb = (seg == 1) ? BloT : BhiT;
#pragma unroll
        for (int i = 0; i < 4; ++i) {
            int c = i * 256 + tid;
            int row = c >> 3;
            int col16 = (c & 7) ^ (row & 7);
            int arow = bm + row; arow = arow < M ? arow : M - 1;
            gload_lds16(Ab + (size_t)arow * K + k0 + (col16 << 3),
                        (char*)As + i * 4096 + wbase);
        }
#pragma unroll
        for (int i = 0; i < 4; ++i) {
            int c = i * 256 + tid;
            int j = c >> 3;
            int col16 = (c & 7) ^ (j & 7);
            gload_lds16(Bb + (size_t)(bn + j) * K + k0 + (col16 << 3),
                        (char*)Bs + i * 4096 + wbase);
        }
        __syncthreads();
#pragma unroll
        for (int kk = 0; kk < 64; kk += 32) {
            bf16x8 a[4], b[4];
            int kb = (kk + fk) >> 3;
#pragma unroll
            for (int m = 0; m < 4; ++m) {
                int row = wm + m * 16 + fr;
                a[m] = *(const bf16x8*)((const char*)As + row * 128 + ((kb ^ (row & 7)) << 4));
            }
#pragma unroll
            for (int n = 0; n < 4; ++n) {
                int col = wn + n * 16 + fr;
                b[n] = *(const bf16x8*)((const char*)Bs + col * 128 + ((kb ^ (col & 7)) << 4));
            }
#pragma unroll
            for (int m = 0; m < 4; ++m)
#pragma unroll
                for (int n = 0; n < 4; ++n)
                    acc[m][n] = __builtin_amdgcn_mfma_f32_16x16x32_bf16(a[m], b[n], acc[m][n], 0, 0, 0);
        }
        __syncthreads();
    }

    const int rbase = (l >> 4) * 4;
#pragma unroll
    for (int m = 0; m < 4; ++m) {
        int row0 = bm + wm + m * 16 + rbase;
#pragma unroll
        for (int n = 0; n < 4; ++n) {
            int col = bn + wn + n * 16 + fr;
#pragma unroll
            for (int rr = 0; rr < 4; ++rr) {
                int rowi = row0 + rr;
                if (rowi < M) C[(size_t)rowi * HC + col] = acc[m][n][rr];
            }
        }
    }
}

// ---------------- conversions ----------------
__global__ void k_cvt_hilo(const float* __restrict__ in, ushort* __restrict__ hi,
                           ushort* __restrict__ lo, int n4) {
    int i = blockIdx.x * blockDim.x + threadIdx.x;
    if (i >= n4) return;
    float4 v = ((const float4*)in)[i];
    ushort4 h, l;
    h.x = f2bf(v.x); l.x = f2bf(v.x - bf2f(h.x));
    h.y = f2bf(v.y); l.y = f2bf(v.y - bf2f(h.y));
    h.z = f2bf(v.z); l.z = f2bf(v.z - bf2f(h.z));
    h.w = f2bf(v.w); l.w = f2bf(v.w - bf2f(h.w));
    ((ushort4*)hi)[i] = h;
    ((ushort4*)lo)[i] = l;
}

__global__ void k_cvt_wT(const float* __restrict__ W, ushort* __restrict__ hiT,
                         ushort* __restrict__ loT, int K, int logK) {
    int id = blockIdx.x * blockDim.x + threadIdx.x;
    if (id >= (HC << logK)) return;
    int nn = id >> logK, k = id & (K - 1);
    float x = W[(size_t)k * HC + nn];
    ushort h = f2bf(x);
    hiT[id] = h;
    loT[id] = f2bf(x - bf2f(h));
}

// ---------------- attention coefficients ----------------
__global__ __launch_bounds__(256) void k_attn(const float* __restrict__ h,
                                              const float* __restrict__ a_src,
                                              const float* __restrict__ a_dst,
                                              float* __restrict__ as,
                                              float* __restrict__ ad, int N) {
    const int local = threadIdx.x & 127;
    const int node = blockIdx.x * 2 + (threadIdx.x >> 7);
    if (node >= N) return;
    const int head = local >> 5;
    const int c = (local & 31) << 2;
    float4 hv = *(const float4*)&h[(size_t)node * HC + (local << 2)];
    float4 sv = *(const float4*)&a_src[head * 128 + c];
    float4 dv = *(const float4*)&a_dst[head * 128 + c];
    float ps = hv.x * sv.x + hv.y * sv.y + hv.z * sv.z + hv.w * sv.w;
    float pd = hv.x * dv.x + hv.y * dv.y + hv.z * dv.z + hv.w * dv.w;
#pragma unroll
    for (int off = 16; off; off >>= 1) {
        ps += __shfl_down(ps, off, 32);
        pd += __shfl_down(pd, off, 32);
    }
    if ((local & 31) == 0) {
        as[node * NH + head] = ps;
        ad[node * NH + head] = pd;
    }
}

// ---------------- CSR build ----------------
__global__ void k_deg(const int* __restrict__ ei, int* __restrict__ deg) {
    int e = blockIdx.x * blockDim.x + threadIdx.x;
    if (e >= NET) return;
    int d = (e < NE) ? ei[NE + e] : (e - NE);
    atomicAdd(&deg[d], 1);
}

__global__ __launch_bounds__(1024) void k_scan(const int* __restrict__ cnt,
                                               int* __restrict__ off, int n) {
    __shared__ int sums[1024];
    const int tid = threadIdx.x;
    const int chunk = (n + 1023) >> 10;
    const int beg = tid * chunk;
    const int end = min(beg + chunk, n);
    int s = 0;
    for (int i = beg; i < end; ++i) s += cnt[i];
    sums[tid] = s;
    __syncthreads();
    for (int d = 1; d < 1024; d <<= 1) {
        int t = (tid >= d) ? sums[tid - d] : 0;
        __syncthreads();
        sums[tid] += t;
        __syncthreads();
    }
    int run = (tid == 0) ? 0 : sums[tid - 1];
    for (int i = beg; i < end; ++i) { off[i] = run; run += cnt[i]; }
    if (tid == 1023) off[n] = sums[1023];
}

__global__ void k_fill(const int* __restrict__ ei,
                       const int* __restrict__ rowptr,
                       int* __restrict__ fillcnt,
                       int* __restrict__ colsrc) {
    int e = blockIdx.x * blockDim.x + threadIdx.x;
    if (e >= NET) return;
    int s, d;
    if (e < NE) { s = ei[e]; d = ei[NE + e]; } else { s = d = e - NE; }
    int pos = rowptr[d] + atomicAdd(&fillcnt[d], 1);
    colsrc[pos] = s;
}

// ---------------- softmax stats + per-edge alpha (planar [4][NET]) --------
// 4 lanes per node (one per head); 64 nodes per 256-thread block.
__global__ __launch_bounds__(256) void k_stats(
    const float* __restrict__ as, const float* __restrict__ ad,
    const int* __restrict__ rowptr, const int* __restrict__ colsrc,
    float* __restrict__ alpha, int N)
{
    const int n = blockIdx.x * 64 + (threadIdx.x >> 2);
    if (n >= N) return;
    const int h = threadIdx.x & 3;
    const int beg = rowptr[n], end = rowptr[n + 1];
    const float adn = ad[n * 4 + h];
    float mh = -3.0e38f;
    for (int e = beg; e < end; ++e) {
        int s = colsrc[e];
        float ev = as[s * 4 + h] + adn;
        ev = ev > 0.f ? ev : 0.2f * ev;
        mh = fmaxf(mh, ev);
    }
    float sum = 0.f;
    float* ah = alpha + (size_t)h * NET;
    for (int e = beg; e < end; ++e) {
        int s = colsrc[e];
        float ev = as[s * 4 + h] + adn;
        ev = ev > 0.f ? ev : 0.2f * ev;
        float x = __expf(ev - mh);
        ah[e] = x;
        sum += x;
    }
    const float dinv = 1.0f / (sum + 1e-16f);
    for (int e = beg; e < end; ++e) ah[e] *= dinv;
}

// ---------------- head-major weighted gather ----------------
// subgroup of 32 lanes per (node, head); head-major block order keeps the
// per-head 25.6 MB z-slice LLC-resident. mode 0: fp32 out; mode 1: bf16 hi/lo.
__global__ __launch_bounds__(256) void k_gather(
    const float* __restrict__ z, const float* __restrict__ alpha,
    const int* __restrict__ rowptr, const int* __restrict__ colsrc,
    const float* __restrict__ bias, float* __restrict__ outf,
    ushort* __restrict__ ohi, ushort* __restrict__ olo, int mode, int N)
{
    const int ng = N >> 3;                       // node-groups per head (N%8==0)
    const int head = blockIdx.x / ng;
    const int node = (blockIdx.x % ng) * 8 + (threadIdx.x >> 5);
    const int lane = threadIdx.x & 31;
    const int beg = rowptr[node], end = rowptr[node + 1];
    const float* __restrict__ zh = z + head * 128 + (lane << 2);
    const float* __restrict__ ah = alpha + (size_t)head * NET;

    float ax = 0.f, ay = 0.f, az = 0.f, aw = 0.f;
    int e = beg;
    for (; e + 2 <= end; e += 2) {
        int s0 = colsrc[e], s1 = colsrc[e + 1];
        float a0 = ah[e], a1 = ah[e + 1];
        float4 v0 = *(const float4*)&zh[(size_t)s0 * HC];
        float4 v1 = *(const float4*)&zh[(size_t)s1 * HC];
        ax += a0 * v0.x + a1 * v1.x;
        ay += a0 * v0.y + a1 * v1.y;
        az += a0 * v0.z + a1 * v1.z;
        aw += a0 * v0.w + a1 * v1.w;
    }
    if (e < end) {
        int s0 = colsrc[e];
        float a0 = ah[e];
        float4 v0 = *(const float4*)&zh[(size_t)s0 * HC];
        ax += a0 * v0.x; ay += a0 * v0.y; az += a0 * v0.z; aw += a0 * v0.w;
    }
    const int col = head * 128 + (lane << 2);
    float4 bv = *(const float4*)&bias[col];
    float rx = fmaxf(ax + bv.x, 0.f), ry = fmaxf(ay + bv.y, 0.f);
    float rz = fmaxf(az + bv.z, 0.f), rw = fmaxf(aw + bv.w, 0.f);
    if (mode == 0) {
        *(float4*)&outf[(size_t)node * HC + col] = make_float4(rx, ry, rz, rw);
    } else {
        ushort4 h, l;
        h.x = f2bf(rx); l.x = f2bf(rx - bf2f(h.x));
        h.y = f2bf(ry); l.y = f2bf(ry - bf2f(h.y));
        h.z = f2bf(rz); l.z = f2bf(rz - bf2f(h.z));
        h.w = f2bf(rw); l.w = f2bf(rw - bf2f(h.w));
        *(ushort4*)&ohi[(size_t)node * HC + col] = h;
        *(ushort4*)&olo[(size_t)node * HC + col] = l;
    }
}

// ---------------- pooling / classifier ----------------
__global__ void k_gcnt(const int* __restrict__ batch, int* __restrict__ gcnt) {
    int n = blockIdx.x * blockDim.x + threadIdx.x;
    if (n < NN) atomicAdd(&gcnt[batch[n]], 1);
}

__global__ __launch_bounds__(128) void k_pool(const float* __restrict__ h,
                                              const int* __restrict__ goff,
                                              const int* __restrict__ gcnt,
                                              float* __restrict__ hg) {
    const int g = blockIdx.x;
    const int tid = threadIdx.x;
    const int beg = goff[g];
    const int cnt = gcnt[g];
    float4 acc = make_float4(0.f, 0.f, 0.f, 0.f);
    for (int r = beg; r < beg + cnt; ++r) {
        float4 v = *(const float4*)&h[(size_t)r * HC + (tid << 2)];
        acc.x += v.x; acc.y += v.y; acc.z += v.z; acc.w += v.w;
    }
    float inv = 1.0f / (float)max(cnt, 1);
    *(float4*)&hg[(size_t)g * HC + (tid << 2)] =
        make_float4(acc.x * inv, acc.y * inv, acc.z * inv, acc.w * inv);
}

__global__ __launch_bounds__(64) void k_cls(const float* __restrict__ hg,
                                            const float* __restrict__ Wc,
                                            const float* __restrict__ bc,
                                            float* __restrict__ out) {
    const int g = blockIdx.x;
    const int lane = threadIdx.x;
#pragma unroll 1
    for (int cls = 0; cls < NCLS; ++cls) {
        float p = 0.f;
#pragma unroll
        for (int j = 0; j < 8; ++j) {
            int c = lane + j * 64;
            p += hg[(size_t)g * HC + c] * Wc[c * NCLS + cls];
        }
#pragma unroll
        for (int off = 32; off; off >>= 1) p += __shfl_down(p, off, 64);
        if (lane == 0) out[g * NCLS + cls] = p + bc[cls];
    }
}

// ---------------- launch ----------------
extern "C" void kernel_launch(void* const* d_in, const int* in_sizes, int n_in,
                              void* d_out, int out_size, void* d_ws, size_t ws_size,
                              hipStream_t stream) {
    const float* x     = (const float*)d_in[0];
    const int*   ei    = (const int*)d_in[1];
    const int*   batch = (const int*)d_in[2];
    const float* W1    = (const float*)d_in[3];
    const float* asrc1 = (const float*)d_in[4];
    const float* adst1 = (const float*)d_in[5];
    const float* b1    = (const float*)d_in[6];
    const float* W2    = (const float*)d_in[7];
    const float* asrc2 = (const float*)d_in[8];
    const float* adst2 = (const float*)d_in[9];
    const float* b2    = (const float*)d_in[10];
    const float* Wc    = (const float*)d_in[11];
    const float* bc    = (const float*)d_in[12];
    float* out = (float*)d_out;
    (void)in_sizes; (void)n_in; (void)out_size; (void)ws_size;

    char* w = (char*)d_ws;
    size_t off = 0;
    auto alloc = [&](size_t bytes) {
        void* p = w + off;
        off += (bytes + 255) & ~(size_t)255;
        return p;
    };
    float* bufA = (float*)alloc((size_t)NN * HC * 4);      // z (GEMM out)
    char*  bufB = (char*)alloc((size_t)NN * HC * 4);       // time-shared region
    ushort* xhi  = (ushort*)(bufB);
    ushort* xlo  = (ushort*)(bufB + (size_t)NN * IND * 2);
    ushort* h1hi = (ushort*)(bufB);
    ushort* h1lo = (ushort*)(bufB + (size_t)NN * HC * 2);
    float*  h2f  = (float*)(bufB);

    float* as_b = (float*)alloc((size_t)NN * NH * 4);
    float* ad_b = (float*)alloc((size_t)NN * NH * 4);
    int* rowptr = (int*)alloc((size_t)(NN + 1) * 4);
    int* deg    = (int*)alloc((size_t)NN * 4);
    int* colsrc = (int*)alloc((size_t)NET * 4);
    int* gcnt   = (int*)alloc((size_t)NG * 4);
    int* goff   = (int*)alloc((size_t)(NG + 1) * 4);
    float* hg   = (float*)alloc((size_t)NG * HC * 4);
    ushort* B1hiT = (ushort*)alloc((size_t)HC * IND * 2);
    ushort* B1loT = (ushort*)alloc((size_t)HC * IND * 2);
    ushort* B2hiT = (ushort*)alloc((size_t)HC * HC * 2);
    ushort* B2loT = (ushort*)alloc((size_t)HC * HC * 2);
    float* alpha  = (float*)alloc((size_t)NH * NET * 4);   // planar [4][NET], 8.8 MB

    const int EB = 256, EG = (NET + EB - 1) / EB;
    const int MT = (NN + 127) / 128;
    const int GATHER_GRID = NH * (NN >> 3);                // head-major

    // ---- conversions ----
    k_cvt_hilo<<<(NN * IND / 4 + 255) / 256, 256, 0, stream>>>(x, xhi, xlo, NN * IND / 4);
    k_cvt_wT<<<(HC * IND + 255) / 256, 256, 0, stream>>>(W1, B1hiT, B1loT, IND, 8);
    k_cvt_wT<<<(HC * HC + 255) / 256, 256, 0, stream>>>(W2, B2hiT, B2loT, HC, 9);

    // ---- CSR build ----
    hipMemsetAsync(deg, 0, (size_t)NN * 4, stream);
    k_deg<<<EG, EB, 0, stream>>>(ei, deg);
    k_scan<<<1, 1024, 0, stream>>>(deg, rowptr, NN);
    hipMemsetAsync(deg, 0, (size_t)NN * 4, stream);
    k_fill<<<EG, EB, 0, stream>>>(ei, rowptr, deg, colsrc);

    // ---- graph offsets ----
    hipMemsetAsync(gcnt, 0, (size_t)NG * 4, stream);
    k_gcnt<<<(NN + 255) / 256, 256, 0, stream>>>(batch, gcnt);
    k_scan<<<1, 1024, 0, stream>>>(gcnt, goff, NG);

    // ================= layer 1 =================
    k_gemm_mfma<<<MT * 4, 256, 0, stream>>>(xhi, xlo, B1hiT, B1loT, bufA, NN, IND);
    k_attn<<<(NN + 1) / 2, 256, 0, stream>>>(bufA, asrc1, adst1, as_b, ad_b, NN);
    k_stats<<<(NN + 63) / 64, 256, 0, stream>>>(as_b, ad_b, rowptr, colsrc, alpha, NN);
    k_gather<<<GATHER_GRID, 256, 0, stream>>>(bufA, alpha, rowptr, colsrc, b1,
                                              h2f, h1hi, h1lo, 1, NN);

    // ================= layer 2 =================
    k_gemm_mfma<<<MT * 4, 256, 0, stream>>>(h1hi, h1lo, B2hiT, B2loT, bufA, NN, HC);
    k_attn<<<(NN + 1) / 2, 256, 0, stream>>>(bufA, asrc2, adst2, as_b, ad_b, NN);
    k_stats<<<(NN + 63) / 64, 256, 0, stream>>>(as_b, ad_b, rowptr, colsrc, alpha, NN);
    k_gather<<<GATHER_GRID, 256, 0, stream>>>(bufA, alpha, rowptr, colsrc, b2,
                                              h2f, h1hi, h1lo, 0, NN);

    // ================= pool + classify =================
    k_pool<<<NG, 128, 0, stream>>>(h2f, goff, gcnt, hg);
    k_cls<<<NG, 64, 0, stream>>>(hg, Wc, bc, out);
}

// Round 4
// 688.967 us; speedup vs baseline: 1.1759x; 1.1759x over previous
//
#include <hip/hip_runtime.h>

// ---------------- problem constants ----------------
#define NN      50000      // nodes
#define NE      500000     // edges (before self loops)
#define NET     550000     // edges + self loops
#define IND     256        // input dim
#define HC      512        // heads*hidden
#define NH      4          // heads
#define NG      512        // graphs
#define NCLS    10

typedef __attribute__((ext_vector_type(8))) short bf16x8;
typedef __attribute__((ext_vector_type(4))) float f32x4;

// ---------------- bf16 split helpers (RNE) ----------------
__device__ __forceinline__ ushort f2bf(float x) {
    unsigned u = __float_as_uint(x);
    u += 0x7fffu + ((u >> 16) & 1u);
    return (ushort)(u >> 16);
}
__device__ __forceinline__ float bf2f(ushort h) {
    return __uint_as_float((unsigned)h << 16);
}

// async global->LDS, 16B per lane. dst must be wave-uniform base (+lane*16 by HW).
__device__ __forceinline__ void gload_lds16(const void* g, void* s) {
    __builtin_amdgcn_global_load_lds(
        (const __attribute__((address_space(1))) unsigned*)g,
        (__attribute__((address_space(3))) unsigned*)s, 16, 0, 0);
}

// ---------------- split-bf16 MFMA GEMM ----------------
// C[M,512] = (Ahi+Alo)[M,K] @ (Bhi+Blo)[K,512]  (minus Alo*Blo, ~2^-18)
__global__ __launch_bounds__(256) void k_gemm_mfma(
    const ushort* __restrict__ Ahi, const ushort* __restrict__ Alo,
    const ushort* __restrict__ BhiT, const ushort* __restrict__ BloT,
    float* __restrict__ C, int M, int K)
{
    __shared__ __align__(16) ushort As[128 * 64];
    __shared__ __align__(16) ushort Bs[128 * 64];

    const int tid = threadIdx.x;
    const int nwg = gridDim.x;
    const int orig = blockIdx.x;
    const int q = nwg >> 3, r = nwg & 7, xcd = orig & 7;
    const int wgid = (xcd < r ? xcd * (q + 1) : r * (q + 1) + (xcd - r) * q) + (orig >> 3);
    const int bm = (wgid >> 2) * 128;
    const int bn = (wgid & 3) * 128;

    const int l = tid & 63;
    const int w = tid >> 6;
    const int wm = (w >> 1) * 64, wn = (w & 1) * 64;
    const int fr = l & 15;
    const int fk = (l >> 4) * 8;

    f32x4 zero = {0.f, 0.f, 0.f, 0.f};
    f32x4 acc[4][4];
#pragma unroll
    for (int m = 0; m < 4; ++m)
#pragma unroll
        for (int n = 0; n < 4; ++n) acc[m][n] = zero;

    const int spseg = K >> 6;
    const int total = 3 * spseg;
    const int wbase = (tid & 0xC0) << 4;

    for (int ks = 0; ks < total; ++ks) {
        int seg = (ks >= spseg) + (ks >= 2 * spseg);
        int k0 = (ks - seg * spseg) << 6;
        const ushort* Ab = (seg == 2) ? Alo : Ahi;
        const ushort* Bb = (seg == 1) ? BloT : BhiT;
#pragma unroll
        for (int i = 0; i < 4; ++i) {
            int c = i * 256 + tid;
            int row = c >> 3;
            int col16 = (c & 7) ^ (row & 7);
            int arow = bm + row; arow = arow < M ? arow : M - 1;
            gload_lds16(Ab + (size_t)arow * K + k0 + (col16 << 3),
                        (char*)As + i * 4096 + wbase);
        }
#pragma unroll
        for (int i = 0; i < 4; ++i) {
            int c = i * 256 + tid;
            int j = c >> 3;
            int col16 = (c & 7) ^ (j & 7);
            gload_lds16(Bb + (size_t)(bn + j) * K + k0 + (col16 << 3),
                        (char*)Bs + i * 4096 + wbase);
        }
        __syncthreads();
#pragma unroll
        for (int kk = 0; kk < 64; kk += 32) {
            bf16x8 a[4], b[4];
            int kb = (kk + fk) >> 3;
#pragma unroll
            for (int m = 0; m < 4; ++m) {
                int row = wm + m * 16 + fr;
                a[m] = *(const bf16x8*)((const char*)As + row * 128 + ((kb ^ (row & 7)) << 4));
            }
#pragma unroll
            for (int n = 0; n < 4; ++n) {
                int col = wn + n * 16 + fr;
                b[n] = *(const bf16x8*)((const char*)Bs + col * 128 + ((kb ^ (col & 7)) << 4));
            }
#pragma unroll
            for (int m = 0; m < 4; ++m)
#pragma unroll
                for (int n = 0; n < 4; ++n)
                    acc[m][n] = __builtin_amdgcn_mfma_f32_16x16x32_bf16(a[m], b[n], acc[m][n], 0, 0, 0);
        }
        __syncthreads();
    }

    const int rbase = (l >> 4) * 4;
#pragma unroll
    for (int m = 0; m < 4; ++m) {
        int row0 = bm + wm + m * 16 + rbase;
#pragma unroll
        for (int n = 0; n < 4; ++n) {
            int col = bn + wn + n * 16 + fr;
#pragma unroll
            for (int rr = 0; rr < 4; ++rr) {
                int rowi = row0 + rr;
                if (rowi < M) C[(size_t)rowi * HC + col] = acc[m][n][rr];
            }
        }
    }
}

// ---------------- conversions ----------------
__global__ void k_cvt_hilo(const float* __restrict__ in, ushort* __restrict__ hi,
                           ushort* __restrict__ lo, int n4) {
    int i = blockIdx.x * blockDim.x + threadIdx.x;
    if (i >= n4) return;
    float4 v = ((const float4*)in)[i];
    ushort4 h, l;
    h.x = f2bf(v.x); l.x = f2bf(v.x - bf2f(h.x));
    h.y = f2bf(v.y); l.y = f2bf(v.y - bf2f(h.y));
    h.z = f2bf(v.z); l.z = f2bf(v.z - bf2f(h.z));
    h.w = f2bf(v.w); l.w = f2bf(v.w - bf2f(h.w));
    ((ushort4*)hi)[i] = h;
    ((ushort4*)lo)[i] = l;
}

__global__ void k_cvt_wT(const float* __restrict__ W, ushort* __restrict__ hiT,
                         ushort* __restrict__ loT, int K, int logK) {
    int id = blockIdx.x * blockDim.x + threadIdx.x;
    if (id >= (HC << logK)) return;
    int nn = id >> logK, k = id & (K - 1);
    float x = W[(size_t)k * HC + nn];
    ushort h = f2bf(x);
    hiT[id] = h;
    loT[id] = f2bf(x - bf2f(h));
}

// ---------------- attention coefficients + bf16 z mirror ----------------
__global__ __launch_bounds__(256) void k_attn(const float* __restrict__ h,
                                              const float* __restrict__ a_src,
                                              const float* __restrict__ a_dst,
                                              float* __restrict__ as,
                                              float* __restrict__ ad,
                                              ushort* __restrict__ zbf, int N) {
    const int local = threadIdx.x & 127;
    const int node = blockIdx.x * 2 + (threadIdx.x >> 7);
    if (node >= N) return;
    const int head = local >> 5;
    const int c = (local & 31) << 2;
    float4 hv = *(const float4*)&h[(size_t)node * HC + (local << 2)];
    // bf16 mirror for the gather kernel (halves its memory demand)
    ushort4 qz;
    qz.x = f2bf(hv.x); qz.y = f2bf(hv.y); qz.z = f2bf(hv.z); qz.w = f2bf(hv.w);
    *(ushort4*)&zbf[(size_t)node * HC + (local << 2)] = qz;
    float4 sv = *(const float4*)&a_src[head * 128 + c];
    float4 dv = *(const float4*)&a_dst[head * 128 + c];
    float ps = hv.x * sv.x + hv.y * sv.y + hv.z * sv.z + hv.w * sv.w;
    float pd = hv.x * dv.x + hv.y * dv.y + hv.z * dv.z + hv.w * dv.w;
#pragma unroll
    for (int off = 16; off; off >>= 1) {
        ps += __shfl_down(ps, off, 32);
        pd += __shfl_down(pd, off, 32);
    }
    if ((local & 31) == 0) {
        as[node * NH + head] = ps;
        ad[node * NH + head] = pd;
    }
}

// ---------------- CSR build ----------------
__global__ void k_deg(const int* __restrict__ ei, int* __restrict__ deg) {
    int e = blockIdx.x * blockDim.x + threadIdx.x;
    if (e >= NET) return;
    int d = (e < NE) ? ei[NE + e] : (e - NE);
    atomicAdd(&deg[d], 1);
}

__global__ __launch_bounds__(1024) void k_scan(const int* __restrict__ cnt,
                                               int* __restrict__ off, int n) {
    __shared__ int sums[1024];
    const int tid = threadIdx.x;
    const int chunk = (n + 1023) >> 10;
    const int beg = tid * chunk;
    const int end = min(beg + chunk, n);
    int s = 0;
    for (int i = beg; i < end; ++i) s += cnt[i];
    sums[tid] = s;
    __syncthreads();
    for (int d = 1; d < 1024; d <<= 1) {
        int t = (tid >= d) ? sums[tid - d] : 0;
        __syncthreads();
        sums[tid] += t;
        __syncthreads();
    }
    int run = (tid == 0) ? 0 : sums[tid - 1];
    for (int i = beg; i < end; ++i) { off[i] = run; run += cnt[i]; }
    if (tid == 1023) off[n] = sums[1023];
}

__global__ void k_fill(const int* __restrict__ ei,
                       const int* __restrict__ rowptr,
                       int* __restrict__ fillcnt,
                       int* __restrict__ colsrc) {
    int e = blockIdx.x * blockDim.x + threadIdx.x;
    if (e >= NET) return;
    int s, d;
    if (e < NE) { s = ei[e]; d = ei[NE + e]; } else { s = d = e - NE; }
    int pos = rowptr[d] + atomicAdd(&fillcnt[d], 1);
    colsrc[pos] = s;
}

// ---------------- softmax stats: unnormalized exp + inverse denom ---------
// 4 lanes per node (one per head); 64 nodes per 256-thread block.
__global__ __launch_bounds__(256) void k_stats(
    const float* __restrict__ as, const float* __restrict__ ad,
    const int* __restrict__ rowptr, const int* __restrict__ colsrc,
    float* __restrict__ alpha, float* __restrict__ dinv, int N)
{
    const int n = blockIdx.x * 64 + (threadIdx.x >> 2);
    if (n >= N) return;
    const int h = threadIdx.x & 3;
    const int beg = rowptr[n], end = rowptr[n + 1];
    const float adn = ad[n * 4 + h];
    float mh = -3.0e38f;
    for (int e = beg; e < end; ++e) {
        int s = colsrc[e];
        float ev = as[s * 4 + h] + adn;
        ev = ev > 0.f ? ev : 0.2f * ev;
        mh = fmaxf(mh, ev);
    }
    float sum = 0.f;
    float* ah = alpha + (size_t)h * NET;
    for (int e = beg; e < end; ++e) {
        int s = colsrc[e];
        float ev = as[s * 4 + h] + adn;
        ev = ev > 0.f ? ev : 0.2f * ev;
        float x = __expf(ev - mh);
        ah[e] = x;
        sum += x;
    }
    dinv[n * 4 + h] = 1.0f / (sum + 1e-16f);
}

// ---------------- head-major weighted gather (bf16 z) ----------------
// subgroup of 32 lanes per (node, head); 4-wide unrolled gather loop.
// mode 0: fp32 out; mode 1: bf16 hi/lo out.
__global__ __launch_bounds__(256) void k_gather(
    const ushort* __restrict__ zb, const float* __restrict__ alpha,
    const float* __restrict__ dinv, const int* __restrict__ rowptr,
    const int* __restrict__ colsrc, const float* __restrict__ bias,
    float* __restrict__ outf, ushort* __restrict__ ohi,
    ushort* __restrict__ olo, int mode, int N)
{
    const int ng = N >> 3;                       // node-groups per head (N%8==0)
    const int head = blockIdx.x / ng;
    const int node = (blockIdx.x % ng) * 8 + (threadIdx.x >> 5);
    const int lane = threadIdx.x & 31;
    const int beg = rowptr[node], end = rowptr[node + 1];
    const ushort* __restrict__ zh = zb + head * 128 + (lane << 2);
    const float* __restrict__ ah = alpha + (size_t)head * NET;

    float ax = 0.f, ay = 0.f, az = 0.f, aw = 0.f;
    int e = beg;
    for (; e + 4 <= end; e += 4) {
        int s0 = colsrc[e], s1 = colsrc[e + 1], s2 = colsrc[e + 2], s3 = colsrc[e + 3];
        float a0 = ah[e], a1 = ah[e + 1], a2 = ah[e + 2], a3 = ah[e + 3];
        ushort4 u0 = *(const ushort4*)&zh[(size_t)s0 * HC];
        ushort4 u1 = *(const ushort4*)&zh[(size_t)s1 * HC];
        ushort4 u2 = *(const ushort4*)&zh[(size_t)s2 * HC];
        ushort4 u3 = *(const ushort4*)&zh[(size_t)s3 * HC];
        ax += a0 * bf2f(u0.x) + a1 * bf2f(u1.x) + a2 * bf2f(u2.x) + a3 * bf2f(u3.x);
        ay += a0 * bf2f(u0.y) + a1 * bf2f(u1.y) + a2 * bf2f(u2.y) + a3 * bf2f(u3.y);
        az += a0 * bf2f(u0.z) + a1 * bf2f(u1.z) + a2 * bf2f(u2.z) + a3 * bf2f(u3.z);
        aw += a0 * bf2f(u0.w) + a1 * bf2f(u1.w) + a2 * bf2f(u2.w) + a3 * bf2f(u3.w);
    }
    for (; e < end; ++e) {
        int s0 = colsrc[e];
        float a0 = ah[e];
        ushort4 u0 = *(const ushort4*)&zh[(size_t)s0 * HC];
        ax += a0 * bf2f(u0.x); ay += a0 * bf2f(u0.y);
        az += a0 * bf2f(u0.z); aw += a0 * bf2f(u0.w);
    }
    const float di = dinv[node * 4 + head];
    const int col = head * 128 + (lane << 2);
    float4 bv = *(const float4*)&bias[col];
    float rx = fmaxf(ax * di + bv.x, 0.f), ry = fmaxf(ay * di + bv.y, 0.f);
    float rz = fmaxf(az * di + bv.z, 0.f), rw = fmaxf(aw * di + bv.w, 0.f);
    if (mode == 0) {
        *(float4*)&outf[(size_t)node * HC + col] = make_float4(rx, ry, rz, rw);
    } else {
        ushort4 h, l;
        h.x = f2bf(rx); l.x = f2bf(rx - bf2f(h.x));
        h.y = f2bf(ry); l.y = f2bf(ry - bf2f(h.y));
        h.z = f2bf(rz); l.z = f2bf(rz - bf2f(h.z));
        h.w = f2bf(rw); l.w = f2bf(rw - bf2f(h.w));
        *(ushort4*)&ohi[(size_t)node * HC + col] = h;
        *(ushort4*)&olo[(size_t)node * HC + col] = l;
    }
}

// ---------------- pooling / classifier ----------------
__global__ void k_gcnt(const int* __restrict__ batch, int* __restrict__ gcnt) {
    int n = blockIdx.x * blockDim.x + threadIdx.x;
    if (n < NN) atomicAdd(&gcnt[batch[n]], 1);
}

__global__ __launch_bounds__(128) void k_pool(const float* __restrict__ h,
                                              const int* __restrict__ goff,
                                              const int* __restrict__ gcnt,
                                              float* __restrict__ hg) {
    const int g = blockIdx.x;
    const int tid = threadIdx.x;
    const int beg = goff[g];
    const int cnt = gcnt[g];
    float4 acc = make_float4(0.f, 0.f, 0.f, 0.f);
    for (int r = beg; r < beg + cnt; ++r) {
        float4 v = *(const float4*)&h[(size_t)r * HC + (tid << 2)];
        acc.x += v.x; acc.y += v.y; acc.z += v.z; acc.w += v.w;
    }
    float inv = 1.0f / (float)max(cnt, 1);
    *(float4*)&hg[(size_t)g * HC + (tid << 2)] =
        make_float4(acc.x * inv, acc.y * inv, acc.z * inv, acc.w * inv);
}

__global__ __launch_bounds__(64) void k_cls(const float* __restrict__ hg,
                                            const float* __restrict__ Wc,
                                            const float* __restrict__ bc,
                                            float* __restrict__ out) {
    const int g = blockIdx.x;
    const int lane = threadIdx.x;
#pragma unroll 1
    for (int cls = 0; cls < NCLS; ++cls) {
        float p = 0.f;
#pragma unroll
        for (int j = 0; j < 8; ++j) {
            int c = lane + j * 64;
            p += hg[(size_t)g * HC + c] * Wc[c * NCLS + cls];
        }
#pragma unroll
        for (int off = 32; off; off >>= 1) p += __shfl_down(p, off, 64);
        if (lane == 0) out[g * NCLS + cls] = p + bc[cls];
    }
}

// ---------------- launch ----------------
extern "C" void kernel_launch(void* const* d_in, const int* in_sizes, int n_in,
                              void* d_out, int out_size, void* d_ws, size_t ws_size,
                              hipStream_t stream) {
    const float* x     = (const float*)d_in[0];
    const int*   ei    = (const int*)d_in[1];
    const int*   batch = (const int*)d_in[2];
    const float* W1    = (const float*)d_in[3];
    const float* asrc1 = (const float*)d_in[4];
    const float* adst1 = (const float*)d_in[5];
    const float* b1    = (const float*)d_in[6];
    const float* W2    = (const float*)d_in[7];
    const float* asrc2 = (const float*)d_in[8];
    const float* adst2 = (const float*)d_in[9];
    const float* b2    = (const float*)d_in[10];
    const float* Wc    = (const float*)d_in[11];
    const float* bc    = (const float*)d_in[12];
    float* out = (float*)d_out;
    (void)in_sizes; (void)n_in; (void)out_size; (void)ws_size;

    // ---- big time-shared region: 204.8 MB, lifetimes verified ----
    // MB offsets:        0            51.2         102.4        153.6
    // phase cvt/GEMM1:   [z1f fp32 102.4        ][xhi 25.6][xlo 25.6][  --  ]
    // phase attn1:       [z1f (read)            ][  --    ][ zbf1 51.2      ]
    // phase gather1:     [h1hi 51.2 ][h1lo 51.2 ][  --    ][ zbf1 (read)    ]
    // phase GEMM2:       [h1 (read)             ][z2f fp32 102.4            ]
    // phase attn2:       [zbf2 51.2 ][  --      ][z2f (read)                ]
    // phase gather2:     [zbf2(read)][h2f fp32 102.4        ][  --          ]
    char* R = (char*)d_ws;
    const size_t MB512 = (size_t)NN * HC;        // 25.6M elements
    float*  z1f  = (float*)R;                                    // +0
    ushort* xhi  = (ushort*)(R + MB512 * 4);                     // +102.4M
    ushort* xlo  = (ushort*)(R + MB512 * 4 + (size_t)NN * IND * 2);
    ushort* zbf1 = (ushort*)(R + MB512 * 6);                     // +153.6M
    ushort* h1hi = (ushort*)R;                                   // +0
    ushort* h1lo = (ushort*)(R + MB512 * 2);                     // +51.2M
    float*  z2f  = (float*)(R + MB512 * 4);                      // +102.4M
    ushort* zbf2 = (ushort*)R;                                   // +0
    float*  h2f  = (float*)(R + MB512 * 2);                      // +51.2M

    char* w = R + MB512 * 8;                                     // +204.8M
    size_t off = 0;
    auto alloc = [&](size_t bytes) {
        void* p = w + off;
        off += (bytes + 255) & ~(size_t)255;
        return p;
    };
    float* as_b = (float*)alloc((size_t)NN * NH * 4);
    float* ad_b = (float*)alloc((size_t)NN * NH * 4);
    float* dinv = (float*)alloc((size_t)NN * NH * 4);
    int* rowptr = (int*)alloc((size_t)(NN + 1) * 4);
    int* deg    = (int*)alloc((size_t)NN * 4);
    int* colsrc = (int*)alloc((size_t)NET * 4);
    int* gcnt   = (int*)alloc((size_t)NG * 4);
    int* goff   = (int*)alloc((size_t)(NG + 1) * 4);
    float* hg   = (float*)alloc((size_t)NG * HC * 4);
    ushort* B1hiT = (ushort*)alloc((size_t)HC * IND * 2);
    ushort* B1loT = (ushort*)alloc((size_t)HC * IND * 2);
    ushort* B2hiT = (ushort*)alloc((size_t)HC * HC * 2);
    ushort* B2loT = (ushort*)alloc((size_t)HC * HC * 2);
    float* alpha  = (float*)alloc((size_t)NH * NET * 4);   // planar [4][NET]

    const int EB = 256, EG = (NET + EB - 1) / EB;
    const int MT = (NN + 127) / 128;
    const int GATHER_GRID = NH * (NN >> 3);                // head-major

    // ---- conversions ----
    k_cvt_hilo<<<(NN * IND / 4 + 255) / 256, 256, 0, stream>>>(x, xhi, xlo, NN * IND / 4);
    k_cvt_wT<<<(HC * IND + 255) / 256, 256, 0, stream>>>(W1, B1hiT, B1loT, IND, 8);
    k_cvt_wT<<<(HC * HC + 255) / 256, 256, 0, stream>>>(W2, B2hiT, B2loT, HC, 9);

    // ---- CSR build ----
    hipMemsetAsync(deg, 0, (size_t)NN * 4, stream);
    k_deg<<<EG, EB, 0, stream>>>(ei, deg);
    k_scan<<<1, 1024, 0, stream>>>(deg, rowptr, NN);
    hipMemsetAsync(deg, 0, (size_t)NN * 4, stream);
    k_fill<<<EG, EB, 0, stream>>>(ei, rowptr, deg, colsrc);

    // ---- graph offsets ----
    hipMemsetAsync(gcnt, 0, (size_t)NG * 4, stream);
    k_gcnt<<<(NN + 255) / 256, 256, 0, stream>>>(batch, gcnt);
    k_scan<<<1, 1024, 0, stream>>>(gcnt, goff, NG);

    // ================= layer 1 =================
    k_gemm_mfma<<<MT * 4, 256, 0, stream>>>(xhi, xlo, B1hiT, B1loT, z1f, NN, IND);
    k_attn<<<(NN + 1) / 2, 256, 0, stream>>>(z1f, asrc1, adst1, as_b, ad_b, zbf1, NN);
    k_stats<<<(NN + 63) / 64, 256, 0, stream>>>(as_b, ad_b, rowptr, colsrc, alpha, dinv, NN);
    k_gather<<<GATHER_GRID, 256, 0, stream>>>(zbf1, alpha, dinv, rowptr, colsrc, b1,
                                              h2f, h1hi, h1lo, 1, NN);

    // ================= layer 2 =================
    k_gemm_mfma<<<MT * 4, 256, 0, stream>>>(h1hi, h1lo, B2hiT, B2loT, z2f, NN, HC);
    k_attn<<<(NN + 1) / 2, 256, 0, stream>>>(z2f, asrc2, adst2, as_b, ad_b, zbf2, NN);
    k_stats<<<(NN + 63) / 64, 256, 0, stream>>>(as_b, ad_b, rowptr, colsrc, alpha, dinv, NN);
    k_gather<<<GATHER_GRID, 256, 0, stream>>>(zbf2, alpha, dinv, rowptr, colsrc, b2,
                                              h2f, h1hi, h1lo, 0, NN);

    // ================= pool + classify =================
    k_pool<<<NG, 128, 0, stream>>>(h2f, goff, gcnt, hg);
    k_cls<<<NG, 64, 0, stream>>>(hg, Wc, bc, out);
}

// Round 5
// 574.882 us; speedup vs baseline: 1.4092x; 1.1984x over previous
//
#include <hip/hip_runtime.h>

// ---------------- problem constants ----------------
#define NN      50000      // nodes
#define NE      500000     // edges (before self loops)
#define NET     550000     // edges + self loops
#define IND     256        // input dim
#define HC      512        // heads*hidden
#define NH      4          // heads
#define NG      512        // graphs
#define NCLS    10

typedef __attribute__((ext_vector_type(8))) _Float16 f16x8;
typedef __attribute__((ext_vector_type(4))) float f32x4;

// ---------------- scalar convert helpers ----------------
__device__ __forceinline__ ushort f2bf(float x) {      // fp32 -> bf16 (RNE)
    unsigned u = __float_as_uint(x);
    u += 0x7fffu + ((u >> 16) & 1u);
    return (ushort)(u >> 16);
}
__device__ __forceinline__ float bf2f(ushort h) {
    return __uint_as_float((unsigned)h << 16);
}
__device__ __forceinline__ ushort f2h(float x) {       // fp32 -> fp16 bits (RNE)
    union { _Float16 h; ushort u; } cv;
    cv.h = (_Float16)x;
    return cv.u;
}

// async global->LDS, 16B per lane. dst must be wave-uniform base (+lane*16 by HW).
__device__ __forceinline__ void gload_lds16(const void* g, void* s) {
    __builtin_amdgcn_global_load_lds(
        (const __attribute__((address_space(1))) unsigned*)g,
        (__attribute__((address_space(3))) unsigned*)s, 16, 0, 0);
}

// ---------------- fp16 MFMA GEMM ----------------
// C[M,512] = A[M,K] @ B[K,512], A/B fp16 (bits in ushort), C fp32 + bf16 mirror.
// BM=BN=128, BK=64, 256 thr = 4 waves (2x2), each wave 64x64 = 4x4 frags of
// 16x16x32. LDS tiles [128][64] fp16, XOR-swizzled via pre-swizzled global src.
__global__ __launch_bounds__(256) void k_gemm_f16(
    const ushort* __restrict__ A, const ushort* __restrict__ BT,
    float* __restrict__ C, ushort* __restrict__ Cbf, int M, int K)
{
    __shared__ __align__(16) ushort As[128 * 64];
    __shared__ __align__(16) ushort Bs[128 * 64];

    const int tid = threadIdx.x;
    const int nwg = gridDim.x;
    const int orig = blockIdx.x;
    const int q = nwg >> 3, r = nwg & 7, xcd = orig & 7;
    const int wgid = (xcd < r ? xcd * (q + 1) : r * (q + 1) + (xcd - r) * q) + (orig >> 3);
    const int bm = (wgid >> 2) * 128;
    const int bn = (wgid & 3) * 128;

    const int l = tid & 63;
    const int w = tid >> 6;
    const int wm = (w >> 1) * 64, wn = (w & 1) * 64;
    const int fr = l & 15;
    const int fk = (l >> 4) * 8;

    f32x4 zero = {0.f, 0.f, 0.f, 0.f};
    f32x4 acc[4][4];
#pragma unroll
    for (int m = 0; m < 4; ++m)
#pragma unroll
        for (int n = 0; n < 4; ++n) acc[m][n] = zero;

    const int nsteps = K >> 6;
    const int wbase = (tid & 0xC0) << 4;       // wave-uniform byte base

    for (int ks = 0; ks < nsteps; ++ks) {
        int k0 = ks << 6;
#pragma unroll
        for (int i = 0; i < 4; ++i) {
            int c = i * 256 + tid;
            int row = c >> 3;
            int col16 = (c & 7) ^ (row & 7);
            int arow = bm + row; arow = arow < M ? arow : M - 1;
            gload_lds16(A + (size_t)arow * K + k0 + (col16 << 3),
                        (char*)As + i * 4096 + wbase);
        }
#pragma unroll
        for (int i = 0; i < 4; ++i) {
            int c = i * 256 + tid;
            int j = c >> 3;
            int col16 = (c & 7) ^ (j & 7);
            gload_lds16(BT + (size_t)(bn + j) * K + k0 + (col16 << 3),
                        (char*)Bs + i * 4096 + wbase);
        }
        __syncthreads();
#pragma unroll
        for (int kk = 0; kk < 64; kk += 32) {
            f16x8 a[4], b[4];
            int kb = (kk + fk) >> 3;
#pragma unroll
            for (int m = 0; m < 4; ++m) {
                int row = wm + m * 16 + fr;
                a[m] = *(const f16x8*)((const char*)As + row * 128 + ((kb ^ (row & 7)) << 4));
            }
#pragma unroll
            for (int n = 0; n < 4; ++n) {
                int col = wn + n * 16 + fr;
                b[n] = *(const f16x8*)((const char*)Bs + col * 128 + ((kb ^ (col & 7)) << 4));
            }
#pragma unroll
            for (int m = 0; m < 4; ++m)
#pragma unroll
                for (int n = 0; n < 4; ++n)
                    acc[m][n] = __builtin_amdgcn_mfma_f32_16x16x32_f16(a[m], b[n], acc[m][n], 0, 0, 0);
        }
        __syncthreads();
    }

    // C/D layout: col = lane&15, row = (lane>>4)*4 + reg
    const int rbase = (l >> 4) * 4;
#pragma unroll
    for (int m = 0; m < 4; ++m) {
        int row0 = bm + wm + m * 16 + rbase;
#pragma unroll
        for (int n = 0; n < 4; ++n) {
            int col = bn + wn + n * 16 + fr;
#pragma unroll
            for (int rr = 0; rr < 4; ++rr) {
                int rowi = row0 + rr;
                if (rowi < M) {
                    float v = acc[m][n][rr];
                    C[(size_t)rowi * HC + col] = v;
                    Cbf[(size_t)rowi * HC + col] = f2bf(v);
                }
            }
        }
    }
}

// ---------------- conversions ----------------
__global__ void k_cvt_f16(const float* __restrict__ in, ushort* __restrict__ o,
                          int n4) {
    int i = blockIdx.x * blockDim.x + threadIdx.x;
    if (i >= n4) return;
    float4 v = ((const float4*)in)[i];
    ushort4 h;
    h.x = f2h(v.x); h.y = f2h(v.y); h.z = f2h(v.z); h.w = f2h(v.w);
    ((ushort4*)o)[i] = h;
}

// W[K][512] -> WT[512][K] fp16
__global__ void k_cvt_wT(const float* __restrict__ W, ushort* __restrict__ hT,
                         int K, int logK) {
    int id = blockIdx.x * blockDim.x + threadIdx.x;
    if (id >= (HC << logK)) return;
    int nn = id >> logK, k = id & (K - 1);
    hT[id] = f2h(W[(size_t)k * HC + nn]);
}

// ---------------- attention coefficients ----------------
__global__ __launch_bounds__(256) void k_attn(const float* __restrict__ h,
                                              const float* __restrict__ a_src,
                                              const float* __restrict__ a_dst,
                                              float* __restrict__ as,
                                              float* __restrict__ ad, int N) {
    const int local = threadIdx.x & 127;
    const int node = blockIdx.x * 2 + (threadIdx.x >> 7);
    if (node >= N) return;
    const int head = local >> 5;
    const int c = (local & 31) << 2;
    float4 hv = *(const float4*)&h[(size_t)node * HC + (local << 2)];
    float4 sv = *(const float4*)&a_src[head * 128 + c];
    float4 dv = *(const float4*)&a_dst[head * 128 + c];
    float ps = hv.x * sv.x + hv.y * sv.y + hv.z * sv.z + hv.w * sv.w;
    float pd = hv.x * dv.x + hv.y * dv.y + hv.z * dv.z + hv.w * dv.w;
#pragma unroll
    for (int off = 16; off; off >>= 1) {
        ps += __shfl_down(ps, off, 32);
        pd += __shfl_down(pd, off, 32);
    }
    if ((local & 31) == 0) {
        as[node * NH + head] = ps;
        ad[node * NH + head] = pd;
    }
}

// ---------------- CSR build ----------------
__global__ void k_deg(const int* __restrict__ ei, int* __restrict__ deg) {
    int e = blockIdx.x * blockDim.x + threadIdx.x;
    if (e >= NET) return;
    int d = (e < NE) ? ei[NE + e] : (e - NE);
    atomicAdd(&deg[d], 1);
}

__global__ __launch_bounds__(1024) void k_scan(const int* __restrict__ cnt,
                                               int* __restrict__ off, int n) {
    __shared__ int sums[1024];
    const int tid = threadIdx.x;
    const int chunk = (n + 1023) >> 10;
    const int beg = tid * chunk;
    const int end = min(beg + chunk, n);
    int s = 0;
    for (int i = beg; i < end; ++i) s += cnt[i];
    sums[tid] = s;
    __syncthreads();
    for (int d = 1; d < 1024; d <<= 1) {
        int t = (tid >= d) ? sums[tid - d] : 0;
        __syncthreads();
        sums[tid] += t;
        __syncthreads();
    }
    int run = (tid == 0) ? 0 : sums[tid - 1];
    for (int i = beg; i < end; ++i) { off[i] = run; run += cnt[i]; }
    if (tid == 1023) off[n] = sums[1023];
}

__global__ void k_fill(const int* __restrict__ ei,
                       const int* __restrict__ rowptr,
                       int* __restrict__ fillcnt,
                       int* __restrict__ colsrc) {
    int e = blockIdx.x * blockDim.x + threadIdx.x;
    if (e >= NET) return;
    int s, d;
    if (e < NE) { s = ei[e]; d = ei[NE + e]; } else { s = d = e - NE; }
    int pos = rowptr[d] + atomicAdd(&fillcnt[d], 1);
    colsrc[pos] = s;
}

// ---------------- softmax stats: unnormalized exp + inverse denom ---------
__global__ __launch_bounds__(256) void k_stats(
    const float* __restrict__ as, const float* __restrict__ ad,
    const int* __restrict__ rowptr, const int* __restrict__ colsrc,
    float* __restrict__ alpha, float* __restrict__ dinv, int N)
{
    const int n = blockIdx.x * 64 + (threadIdx.x >> 2);
    if (n >= N) return;
    const int h = threadIdx.x & 3;
    const int beg = rowptr[n], end = rowptr[n + 1];
    const float adn = ad[n * 4 + h];
    float mh = -3.0e38f;
    for (int e = beg; e < end; ++e) {
        int s = colsrc[e];
        float ev = as[s * 4 + h] + adn;
        ev = ev > 0.f ? ev : 0.2f * ev;
        mh = fmaxf(mh, ev);
    }
    float sum = 0.f;
    float* ah = alpha + (size_t)h * NET;
    for (int e = beg; e < end; ++e) {
        int s = colsrc[e];
        float ev = as[s * 4 + h] + adn;
        ev = ev > 0.f ? ev : 0.2f * ev;
        float x = __expf(ev - mh);
        ah[e] = x;
        sum += x;
    }
    dinv[n * 4 + h] = 1.0f / (sum + 1e-16f);
}

// ---------------- head-major weighted gather (bf16 z) ----------------
// subgroup of 32 lanes per (node, head); mode 0: fp32 out; mode 1: fp16 out.
__global__ __launch_bounds__(256) void k_gather(
    const ushort* __restrict__ zb, const float* __restrict__ alpha,
    const float* __restrict__ dinv, const int* __restrict__ rowptr,
    const int* __restrict__ colsrc, const float* __restrict__ bias,
    float* __restrict__ outf, ushort* __restrict__ oh16, int mode, int N)
{
    const int ng = N >> 3;                       // node-groups per head
    const int head = blockIdx.x / ng;
    const int node = (blockIdx.x % ng) * 8 + (threadIdx.x >> 5);
    const int lane = threadIdx.x & 31;
    const int beg = rowptr[node], end = rowptr[node + 1];
    const ushort* __restrict__ zh = zb + head * 128 + (lane << 2);
    const float* __restrict__ ah = alpha + (size_t)head * NET;

    float ax = 0.f, ay = 0.f, az = 0.f, aw = 0.f;
    int e = beg;
    for (; e + 4 <= end; e += 4) {
        int s0 = colsrc[e], s1 = colsrc[e + 1], s2 = colsrc[e + 2], s3 = colsrc[e + 3];
        float a0 = ah[e], a1 = ah[e + 1], a2 = ah[e + 2], a3 = ah[e + 3];
        ushort4 u0 = *(const ushort4*)&zh[(size_t)s0 * HC];
        ushort4 u1 = *(const ushort4*)&zh[(size_t)s1 * HC];
        ushort4 u2 = *(const ushort4*)&zh[(size_t)s2 * HC];
        ushort4 u3 = *(const ushort4*)&zh[(size_t)s3 * HC];
        ax += a0 * bf2f(u0.x) + a1 * bf2f(u1.x) + a2 * bf2f(u2.x) + a3 * bf2f(u3.x);
        ay += a0 * bf2f(u0.y) + a1 * bf2f(u1.y) + a2 * bf2f(u2.y) + a3 * bf2f(u3.y);
        az += a0 * bf2f(u0.z) + a1 * bf2f(u1.z) + a2 * bf2f(u2.z) + a3 * bf2f(u3.z);
        aw += a0 * bf2f(u0.w) + a1 * bf2f(u1.w) + a2 * bf2f(u2.w) + a3 * bf2f(u3.w);
    }
    for (; e < end; ++e) {
        int s0 = colsrc[e];
        float a0 = ah[e];
        ushort4 u0 = *(const ushort4*)&zh[(size_t)s0 * HC];
        ax += a0 * bf2f(u0.x); ay += a0 * bf2f(u0.y);
        az += a0 * bf2f(u0.z); aw += a0 * bf2f(u0.w);
    }
    const float di = dinv[node * 4 + head];
    const int col = head * 128 + (lane << 2);
    float4 bv = *(const float4*)&bias[col];
    float rx = fmaxf(ax * di + bv.x, 0.f), ry = fmaxf(ay * di + bv.y, 0.f);
    float rz = fmaxf(az * di + bv.z, 0.f), rw = fmaxf(aw * di + bv.w, 0.f);
    if (mode == 0) {
        *(float4*)&outf[(size_t)node * HC + col] = make_float4(rx, ry, rz, rw);
    } else {
        ushort4 h;
        h.x = f2h(rx); h.y = f2h(ry); h.z = f2h(rz); h.w = f2h(rw);
        *(ushort4*)&oh16[(size_t)node * HC + col] = h;
    }
}

// ---------------- pooling / classifier ----------------
__global__ void k_gcnt(const int* __restrict__ batch, int* __restrict__ gcnt) {
    int n = blockIdx.x * blockDim.x + threadIdx.x;
    if (n < NN) atomicAdd(&gcnt[batch[n]], 1);
}

__global__ __launch_bounds__(128) void k_pool(const float* __restrict__ h,
                                              const int* __restrict__ goff,
                                              const int* __restrict__ gcnt,
                                              float* __restrict__ hg) {
    const int g = blockIdx.x;
    const int tid = threadIdx.x;
    const int beg = goff[g];
    const int cnt = gcnt[g];
    float4 acc = make_float4(0.f, 0.f, 0.f, 0.f);
    for (int r = beg; r < beg + cnt; ++r) {
        float4 v = *(const float4*)&h[(size_t)r * HC + (tid << 2)];
        acc.x += v.x; acc.y += v.y; acc.z += v.z; acc.w += v.w;
    }
    float inv = 1.0f / (float)max(cnt, 1);
    *(float4*)&hg[(size_t)g * HC + (tid << 2)] =
        make_float4(acc.x * inv, acc.y * inv, acc.z * inv, acc.w * inv);
}

__global__ __launch_bounds__(64) void k_cls(const float* __restrict__ hg,
                                            const float* __restrict__ Wc,
                                            const float* __restrict__ bc,
                                            float* __restrict__ out) {
    const int g = blockIdx.x;
    const int lane = threadIdx.x;
#pragma unroll 1
    for (int cls = 0; cls < NCLS; ++cls) {
        float p = 0.f;
#pragma unroll
        for (int j = 0; j < 8; ++j) {
            int c = lane + j * 64;
            p += hg[(size_t)g * HC + c] * Wc[c * NCLS + cls];
        }
#pragma unroll
        for (int off = 32; off; off >>= 1) p += __shfl_down(p, off, 64);
        if (lane == 0) out[g * NCLS + cls] = p + bc[cls];
    }
}

// ---------------- launch ----------------
extern "C" void kernel_launch(void* const* d_in, const int* in_sizes, int n_in,
                              void* d_out, int out_size, void* d_ws, size_t ws_size,
                              hipStream_t stream) {
    const float* x     = (const float*)d_in[0];
    const int*   ei    = (const int*)d_in[1];
    const int*   batch = (const int*)d_in[2];
    const float* W1    = (const float*)d_in[3];
    const float* asrc1 = (const float*)d_in[4];
    const float* adst1 = (const float*)d_in[5];
    const float* b1    = (const float*)d_in[6];
    const float* W2    = (const float*)d_in[7];
    const float* asrc2 = (const float*)d_in[8];
    const float* adst2 = (const float*)d_in[9];
    const float* b2    = (const float*)d_in[10];
    const float* Wc    = (const float*)d_in[11];
    const float* bc    = (const float*)d_in[12];
    float* out = (float*)d_out;
    (void)in_sizes; (void)n_in; (void)out_size; (void)ws_size;

    // ---- big time-shared region: 204.8 MB, lifetimes (sequential on stream):
    // MB offsets:       0             102.4        153.6        204.8
    // cvt/GEMM1:        [z1f fp32    ][zbf1 51.2  ][xf16 25.6][--]
    // attn1:            [z1f (read)  ][zbf1 live  ][   --       ]
    // gather1:          [z1f dead    ][zbf1 (read)][h1f16 51.2  ]
    // GEMM2:            [z2f fp32    ][zbf2 51.2  ][h1f16 (read)]
    // attn2:            [z2f (read)  ][zbf2 live  ][   --       ]
    // gather2:          [h2f fp32    ][zbf2 (read)][   --       ]
    // pool:             [h2f (read)  ]
    char* R = (char*)d_ws;
    const size_t MB512 = (size_t)NN * HC;        // 25.6M elements
    float*  z1f   = (float*)R;
    float*  z2f   = (float*)R;
    float*  h2f   = (float*)R;
    ushort* zbf1  = (ushort*)(R + MB512 * 4);
    ushort* zbf2  = (ushort*)(R + MB512 * 4);
    ushort* xf16  = (ushort*)(R + MB512 * 6);
    ushort* h1f16 = (ushort*)(R + MB512 * 6);

    char* w = R + MB512 * 8;
    size_t off = 0;
    auto alloc = [&](size_t bytes) {
        void* p = w + off;
        off += (bytes + 255) & ~(size_t)255;
        return p;
    };
    float* as_b = (float*)alloc((size_t)NN * NH * 4);
    float* ad_b = (float*)alloc((size_t)NN * NH * 4);
    float* dinv = (float*)alloc((size_t)NN * NH * 4);
    int* rowptr = (int*)alloc((size_t)(NN + 1) * 4);
    int* deg    = (int*)alloc((size_t)NN * 4);
    int* colsrc = (int*)alloc((size_t)NET * 4);
    int* gcnt   = (int*)alloc((size_t)NG * 4);
    int* goff   = (int*)alloc((size_t)(NG + 1) * 4);
    float* hg   = (float*)alloc((size_t)NG * HC * 4);
    ushort* W1T = (ushort*)alloc((size_t)HC * IND * 2);
    ushort* W2T = (ushort*)alloc((size_t)HC * HC * 2);
    float* alpha = (float*)alloc((size_t)NH * NET * 4);   // planar [4][NET]

    const int EB = 256, EG = (NET + EB - 1) / EB;
    const int MT = (NN + 127) / 128;
    const int GATHER_GRID = NH * (NN >> 3);                // head-major

    // ---- conversions ----
    k_cvt_f16<<<(NN * IND / 4 + 255) / 256, 256, 0, stream>>>(x, xf16, NN * IND / 4);
    k_cvt_wT<<<(HC * IND + 255) / 256, 256, 0, stream>>>(W1, W1T, IND, 8);
    k_cvt_wT<<<(HC * HC + 255) / 256, 256, 0, stream>>>(W2, W2T, HC, 9);

    // ---- CSR build ----
    hipMemsetAsync(deg, 0, (size_t)NN * 4, stream);
    k_deg<<<EG, EB, 0, stream>>>(ei, deg);
    k_scan<<<1, 1024, 0, stream>>>(deg, rowptr, NN);
    hipMemsetAsync(deg, 0, (size_t)NN * 4, stream);
    k_fill<<<EG, EB, 0, stream>>>(ei, rowptr, deg, colsrc);

    // ---- graph offsets ----
    hipMemsetAsync(gcnt, 0, (size_t)NG * 4, stream);
    k_gcnt<<<(NN + 255) / 256, 256, 0, stream>>>(batch, gcnt);
    k_scan<<<1, 1024, 0, stream>>>(gcnt, goff, NG);

    // ================= layer 1 =================
    k_gemm_f16<<<MT * 4, 256, 0, stream>>>(xf16, W1T, z1f, zbf1, NN, IND);
    k_attn<<<(NN + 1) / 2, 256, 0, stream>>>(z1f, asrc1, adst1, as_b, ad_b, NN);
    k_stats<<<(NN + 63) / 64, 256, 0, stream>>>(as_b, ad_b, rowptr, colsrc, alpha, dinv, NN);
    k_gather<<<GATHER_GRID, 256, 0, stream>>>(zbf1, alpha, dinv, rowptr, colsrc, b1,
                                              h2f, h1f16, 1, NN);

    // ================= layer 2 =================
    k_gemm_f16<<<MT * 4, 256, 0, stream>>>(h1f16, W2T, z2f, zbf2, NN, HC);
    k_attn<<<(NN + 1) / 2, 256, 0, stream>>>(z2f, asrc2, adst2, as_b, ad_b, NN);
    k_stats<<<(NN + 63) / 64, 256, 0, stream>>>(as_b, ad_b, rowptr, colsrc, alpha, dinv, NN);
    k_gather<<<GATHER_GRID, 256, 0, stream>>>(zbf2, alpha, dinv, rowptr, colsrc, b2,
                                              h2f, h1f16, 0, NN);

    // ================= pool + classify =================
    k_pool<<<NG, 128, 0, stream>>>(h2f, goff, gcnt, hg);
    k_cls<<<NG, 64, 0, stream>>>(hg, Wc, bc, out);
}

// Round 6
// 517.774 us; speedup vs baseline: 1.5647x; 1.1103x over previous
//
#include <hip/hip_runtime.h>

// ---------------- problem constants ----------------
#define NN      50000      // nodes
#define NE      500000     // edges (before self loops)
#define NET     550000     // edges + self loops
#define IND     256        // input dim
#define HC      512        // heads*hidden
#define NH      4          // heads
#define NG      512        // graphs
#define NCLS    10

typedef __attribute__((ext_vector_type(8))) _Float16 f16x8;
typedef __attribute__((ext_vector_type(4))) float f32x4;

// ---------------- scalar convert helpers ----------------
__device__ __forceinline__ ushort f2bf(float x) {      // fp32 -> bf16 (RNE)
    unsigned u = __float_as_uint(x);
    u += 0x7fffu + ((u >> 16) & 1u);
    return (ushort)(u >> 16);
}
__device__ __forceinline__ float bf2f(ushort h) {
    return __uint_as_float((unsigned)h << 16);
}
__device__ __forceinline__ ushort f2h(float x) {       // fp32 -> fp16 bits (RNE)
    union { _Float16 h; ushort u; } cv;
    cv.h = (_Float16)x;
    return cv.u;
}

// async global->LDS, 16B per lane. dst must be wave-uniform base (+lane*16 by HW).
__device__ __forceinline__ void gload_lds16(const void* g, void* s) {
    __builtin_amdgcn_global_load_lds(
        (const __attribute__((address_space(1))) unsigned*)g,
        (__attribute__((address_space(3))) unsigned*)s, 16, 0, 0);
}

// ---------------- fp16 MFMA GEMM + fused attention coefficients ----------
// zbf[M,512] = bf16(A[M,K] @ B[K,512]);  as/ad[row,head] = dot(z_row_head, a_*)
// computed from fp32 acc in-register (block covers 128 rows x one head).
// BM=BN=128, BK=64, 256 thr = 4 waves (2x2), 16x16x32 f16 MFMA.
__global__ __launch_bounds__(256) void k_gemm_f16(
    const ushort* __restrict__ A, const ushort* __restrict__ BT,
    const float* __restrict__ a_srcv, const float* __restrict__ a_dstv,
    ushort* __restrict__ Cbf, float* __restrict__ as_b, float* __restrict__ ad_b,
    int M, int K)
{
    __shared__ __align__(16) ushort As[128 * 64];
    __shared__ __align__(16) ushort Bs[128 * 64];
    __shared__ float sred[2][128];

    const int tid = threadIdx.x;
    const int nwg = gridDim.x;
    const int orig = blockIdx.x;
    const int q = nwg >> 3, r = nwg & 7, xcd = orig & 7;
    const int wgid = (xcd < r ? xcd * (q + 1) : r * (q + 1) + (xcd - r) * q) + (orig >> 3);
    const int bm = (wgid >> 2) * 128;
    const int bn = (wgid & 3) * 128;

    const int l = tid & 63;
    const int w = tid >> 6;
    const int wm = (w >> 1) * 64, wn = (w & 1) * 64;
    const int fr = l & 15;
    const int fk = (l >> 4) * 8;

    if (tid < 128) { sred[0][tid] = 0.f; sred[1][tid] = 0.f; }

    f32x4 zero = {0.f, 0.f, 0.f, 0.f};
    f32x4 acc[4][4];
#pragma unroll
    for (int m = 0; m < 4; ++m)
#pragma unroll
        for (int n = 0; n < 4; ++n) acc[m][n] = zero;

    const int nsteps = K >> 6;
    const int wbase = (tid & 0xC0) << 4;       // wave-uniform byte base

    for (int ks = 0; ks < nsteps; ++ks) {
        int k0 = ks << 6;
#pragma unroll
        for (int i = 0; i < 4; ++i) {
            int c = i * 256 + tid;
            int row = c >> 3;
            int col16 = (c & 7) ^ (row & 7);
            int arow = bm + row; arow = arow < M ? arow : M - 1;
            gload_lds16(A + (size_t)arow * K + k0 + (col16 << 3),
                        (char*)As + i * 4096 + wbase);
        }
#pragma unroll
        for (int i = 0; i < 4; ++i) {
            int c = i * 256 + tid;
            int j = c >> 3;
            int col16 = (c & 7) ^ (j & 7);
            gload_lds16(BT + (size_t)(bn + j) * K + k0 + (col16 << 3),
                        (char*)Bs + i * 4096 + wbase);
        }
        __syncthreads();
#pragma unroll
        for (int kk = 0; kk < 64; kk += 32) {
            f16x8 a[4], b[4];
            int kb = (kk + fk) >> 3;
#pragma unroll
            for (int m = 0; m < 4; ++m) {
                int row = wm + m * 16 + fr;
                a[m] = *(const f16x8*)((const char*)As + row * 128 + ((kb ^ (row & 7)) << 4));
            }
#pragma unroll
            for (int n = 0; n < 4; ++n) {
                int col = wn + n * 16 + fr;
                b[n] = *(const f16x8*)((const char*)Bs + col * 128 + ((kb ^ (col & 7)) << 4));
            }
#pragma unroll
            for (int m = 0; m < 4; ++m)
#pragma unroll
                for (int n = 0; n < 4; ++n)
                    acc[m][n] = __builtin_amdgcn_mfma_f32_16x16x32_f16(a[m], b[n], acc[m][n], 0, 0, 0);
        }
        __syncthreads();
    }

    // ---- epilogue: bf16 z mirror + fused as/ad ----
    // C/D layout: col = lane&15, row = (lane>>4)*4 + reg
    const int hh = bn >> 7;                    // this block's head
    float asl[4], adl[4];
#pragma unroll
    for (int n = 0; n < 4; ++n) {
        int c = wn + n * 16 + fr;
        asl[n] = a_srcv[hh * 128 + c];
        adl[n] = a_dstv[hh * 128 + c];
    }
    const int rbase = (l >> 4) * 4;
#pragma unroll
    for (int m = 0; m < 4; ++m) {
#pragma unroll
        for (int rr = 0; rr < 4; ++rr) {
            int rloc = wm + m * 16 + rbase + rr;
            int rowi = bm + rloc;
            float ps = 0.f, pd = 0.f;
#pragma unroll
            for (int n = 0; n < 4; ++n) {
                float v = acc[m][n][rr];
                ps += v * asl[n];
                pd += v * adl[n];
                if (rowi < M) Cbf[(size_t)rowi * HC + bn + wn + n * 16 + fr] = f2bf(v);
            }
#pragma unroll
            for (int off = 1; off < 16; off <<= 1) {
                ps += __shfl_xor(ps, off, 64);
                pd += __shfl_xor(pd, off, 64);
            }
            if (fr == 0) {
                atomicAdd(&sred[0][rloc], ps);
                atomicAdd(&sred[1][rloc], pd);
            }
        }
    }
    __syncthreads();
    if (tid < 128) {
        int rowi = bm + tid;
        if (rowi < M) {
            as_b[rowi * 4 + hh] = sred[0][tid];
            ad_b[rowi * 4 + hh] = sred[1][tid];
        }
    }
}

// ---------------- conversions ----------------
__global__ void k_cvt_f16(const float* __restrict__ in, ushort* __restrict__ o,
                          int n4) {
    int i = blockIdx.x * blockDim.x + threadIdx.x;
    if (i >= n4) return;
    float4 v = ((const float4*)in)[i];
    ushort4 h;
    h.x = f2h(v.x); h.y = f2h(v.y); h.z = f2h(v.z); h.w = f2h(v.w);
    ((ushort4*)o)[i] = h;
}

// W[K][512] -> WT[512][K] fp16
__global__ void k_cvt_wT(const float* __restrict__ W, ushort* __restrict__ hT,
                         int K, int logK) {
    int id = blockIdx.x * blockDim.x + threadIdx.x;
    if (id >= (HC << logK)) return;
    int nn = id >> logK, k = id & (K - 1);
    hT[id] = f2h(W[(size_t)k * HC + nn]);
}

// ---------------- CSR build ----------------
__global__ void k_deg(const int* __restrict__ ei, int* __restrict__ deg) {
    int e = blockIdx.x * blockDim.x + threadIdx.x;
    if (e >= NET) return;
    int d = (e < NE) ? ei[NE + e] : (e - NE);
    atomicAdd(&deg[d], 1);
}

__global__ __launch_bounds__(1024) void k_scan(const int* __restrict__ cnt,
                                               int* __restrict__ off, int n) {
    __shared__ int sums[1024];
    const int tid = threadIdx.x;
    const int chunk = (n + 1023) >> 10;
    const int beg = tid * chunk;
    const int end = min(beg + chunk, n);
    int s = 0;
    for (int i = beg; i < end; ++i) s += cnt[i];
    sums[tid] = s;
    __syncthreads();
    for (int d = 1; d < 1024; d <<= 1) {
        int t = (tid >= d) ? sums[tid - d] : 0;
        __syncthreads();
        sums[tid] += t;
        __syncthreads();
    }
    int run = (tid == 0) ? 0 : sums[tid - 1];
    for (int i = beg; i < end; ++i) { off[i] = run; run += cnt[i]; }
    if (tid == 1023) off[n] = sums[1023];
}

__global__ void k_fill(const int* __restrict__ ei,
                       const int* __restrict__ rowptr,
                       int* __restrict__ fillcnt,
                       int* __restrict__ colsrc) {
    int e = blockIdx.x * blockDim.x + threadIdx.x;
    if (e >= NET) return;
    int s, d;
    if (e < NE) { s = ei[e]; d = ei[NE + e]; } else { s = d = e - NE; }
    int pos = rowptr[d] + atomicAdd(&fillcnt[d], 1);
    colsrc[pos] = s;
}

// ---------------- softmax stats: unnormalized exp + inverse denom ---------
// alpha edge-major [NET][4] so the gather's 4 head-subgroups share lines.
__global__ __launch_bounds__(256) void k_stats(
    const float* __restrict__ as, const float* __restrict__ ad,
    const int* __restrict__ rowptr, const int* __restrict__ colsrc,
    float* __restrict__ alpha, float* __restrict__ dinv, int N)
{
    const int n = blockIdx.x * 64 + (threadIdx.x >> 2);
    if (n >= N) return;
    const int h = threadIdx.x & 3;
    const int beg = rowptr[n], end = rowptr[n + 1];
    const float adn = ad[n * 4 + h];
    float mh = -3.0e38f;
    for (int e = beg; e < end; ++e) {
        int s = colsrc[e];
        float ev = as[s * 4 + h] + adn;
        ev = ev > 0.f ? ev : 0.2f * ev;
        mh = fmaxf(mh, ev);
    }
    float sum = 0.f;
    for (int e = beg; e < end; ++e) {
        int s = colsrc[e];
        float ev = as[s * 4 + h] + adn;
        ev = ev > 0.f ? ev : 0.2f * ev;
        float x = __expf(ev - mh);
        alpha[(size_t)e * 4 + h] = x;
        sum += x;
    }
    dinv[n * 4 + h] = 1.0f / (sum + 1e-16f);
}

// ---------------- unified all-heads weighted gather (bf16 z) --------------
// one 128-thread block per node: 4 subgroups (one per head) walk the edge
// list in lockstep, so each edge's full 1KB z row is touched once.
// mode 0: fp32 out; mode 1: fp16 out.
__global__ __launch_bounds__(128) void k_gather(
    const ushort* __restrict__ zb, const float* __restrict__ alpha,
    const float* __restrict__ dinv, const int* __restrict__ rowptr,
    const int* __restrict__ colsrc, const float* __restrict__ bias,
    float* __restrict__ outf, ushort* __restrict__ oh16, int mode)
{
    const int node = blockIdx.x;
    const int tid = threadIdx.x;
    const int head = tid >> 5, lane = tid & 31;
    const int beg = rowptr[node], end = rowptr[node + 1];
    const ushort* __restrict__ zh = zb + head * 128 + (lane << 2);
    const float* __restrict__ ah = alpha + head;

    float ax = 0.f, ay = 0.f, az = 0.f, aw = 0.f;
    int e = beg;
    for (; e + 2 <= end; e += 2) {
        int s0 = colsrc[e], s1 = colsrc[e + 1];
        float a0 = ah[(size_t)e * 4], a1 = ah[(size_t)(e + 1) * 4];
        ushort4 u0 = *(const ushort4*)&zh[(size_t)s0 * HC];
        ushort4 u1 = *(const ushort4*)&zh[(size_t)s1 * HC];
        ax += a0 * bf2f(u0.x) + a1 * bf2f(u1.x);
        ay += a0 * bf2f(u0.y) + a1 * bf2f(u1.y);
        az += a0 * bf2f(u0.z) + a1 * bf2f(u1.z);
        aw += a0 * bf2f(u0.w) + a1 * bf2f(u1.w);
    }
    if (e < end) {
        int s0 = colsrc[e];
        float a0 = ah[(size_t)e * 4];
        ushort4 u0 = *(const ushort4*)&zh[(size_t)s0 * HC];
        ax += a0 * bf2f(u0.x); ay += a0 * bf2f(u0.y);
        az += a0 * bf2f(u0.z); aw += a0 * bf2f(u0.w);
    }
    const float di = dinv[node * 4 + head];
    const int col = head * 128 + (lane << 2);
    float4 bv = *(const float4*)&bias[col];
    float rx = fmaxf(ax * di + bv.x, 0.f), ry = fmaxf(ay * di + bv.y, 0.f);
    float rz = fmaxf(az * di + bv.z, 0.f), rw = fmaxf(aw * di + bv.w, 0.f);
    if (mode == 0) {
        *(float4*)&outf[(size_t)node * HC + col] = make_float4(rx, ry, rz, rw);
    } else {
        ushort4 h;
        h.x = f2h(rx); h.y = f2h(ry); h.z = f2h(rz); h.w = f2h(rw);
        *(ushort4*)&oh16[(size_t)node * HC + col] = h;
    }
}

// ---------------- pooling / classifier ----------------
__global__ void k_gcnt(const int* __restrict__ batch, int* __restrict__ gcnt) {
    int n = blockIdx.x * blockDim.x + threadIdx.x;
    if (n < NN) atomicAdd(&gcnt[batch[n]], 1);
}

__global__ __launch_bounds__(128) void k_pool(const float* __restrict__ h,
                                              const int* __restrict__ goff,
                                              const int* __restrict__ gcnt,
                                              float* __restrict__ hg) {
    const int g = blockIdx.x;
    const int tid = threadIdx.x;
    const int beg = goff[g];
    const int cnt = gcnt[g];
    float4 acc = make_float4(0.f, 0.f, 0.f, 0.f);
    for (int r = beg; r < beg + cnt; ++r) {
        float4 v = *(const float4*)&h[(size_t)r * HC + (tid << 2)];
        acc.x += v.x; acc.y += v.y; acc.z += v.z; acc.w += v.w;
    }
    float inv = 1.0f / (float)max(cnt, 1);
    *(float4*)&hg[(size_t)g * HC + (tid << 2)] =
        make_float4(acc.x * inv, acc.y * inv, acc.z * inv, acc.w * inv);
}

__global__ __launch_bounds__(64) void k_cls(const float* __restrict__ hg,
                                            const float* __restrict__ Wc,
                                            const float* __restrict__ bc,
                                            float* __restrict__ out) {
    const int g = blockIdx.x;
    const int lane = threadIdx.x;
#pragma unroll 1
    for (int cls = 0; cls < NCLS; ++cls) {
        float p = 0.f;
#pragma unroll
        for (int j = 0; j < 8; ++j) {
            int c = lane + j * 64;
            p += hg[(size_t)g * HC + c] * Wc[c * NCLS + cls];
        }
#pragma unroll
        for (int off = 32; off; off >>= 1) p += __shfl_down(p, off, 64);
        if (lane == 0) out[g * NCLS + cls] = p + bc[cls];
    }
}

// ---------------- launch ----------------
extern "C" void kernel_launch(void* const* d_in, const int* in_sizes, int n_in,
                              void* d_out, int out_size, void* d_ws, size_t ws_size,
                              hipStream_t stream) {
    const float* x     = (const float*)d_in[0];
    const int*   ei    = (const int*)d_in[1];
    const int*   batch = (const int*)d_in[2];
    const float* W1    = (const float*)d_in[3];
    const float* asrc1 = (const float*)d_in[4];
    const float* adst1 = (const float*)d_in[5];
    const float* b1    = (const float*)d_in[6];
    const float* W2    = (const float*)d_in[7];
    const float* asrc2 = (const float*)d_in[8];
    const float* adst2 = (const float*)d_in[9];
    const float* b2    = (const float*)d_in[10];
    const float* Wc    = (const float*)d_in[11];
    const float* bc    = (const float*)d_in[12];
    float* out = (float*)d_out;
    (void)in_sizes; (void)n_in; (void)out_size; (void)ws_size;

    // ---- big time-shared region (204.8 MB), lifetimes sequential on stream:
    // MB offsets:   0              51.2           102.4
    // cvt/GEMM1:    [zbf1 51.2    ][xf16 25.6 ][--][    --      ]
    // stats/gath1:  [zbf1 (read)  ][h1f16 51.2    ][    --      ]
    // GEMM2:        [zbf2 51.2    ][h1f16 (read)  ][    --      ]
    // stats/gath2:  [zbf2 (read)  ][  --          ][h2f 102.4   ]
    // pool:         [  --         ][  --          ][h2f (read)  ]
    char* R = (char*)d_ws;
    const size_t MB512 = (size_t)NN * HC;        // 25.6M elements
    ushort* zbf1  = (ushort*)R;
    ushort* zbf2  = (ushort*)R;
    ushort* xf16  = (ushort*)(R + MB512 * 2);
    ushort* h1f16 = (ushort*)(R + MB512 * 2);
    float*  h2f   = (float*)(R + MB512 * 4);

    char* w = R + MB512 * 8;
    size_t off = 0;
    auto alloc = [&](size_t bytes) {
        void* p = w + off;
        off += (bytes + 255) & ~(size_t)255;
        return p;
    };
    float* as_b = (float*)alloc((size_t)NN * NH * 4);
    float* ad_b = (float*)alloc((size_t)NN * NH * 4);
    float* dinv = (float*)alloc((size_t)NN * NH * 4);
    int* rowptr = (int*)alloc((size_t)(NN + 1) * 4);
    int* deg    = (int*)alloc((size_t)NN * 4);
    int* colsrc = (int*)alloc((size_t)NET * 4);
    int* gcnt   = (int*)alloc((size_t)NG * 4);
    int* goff   = (int*)alloc((size_t)(NG + 1) * 4);
    float* hg   = (float*)alloc((size_t)NG * HC * 4);
    ushort* W1T = (ushort*)alloc((size_t)HC * IND * 2);
    ushort* W2T = (ushort*)alloc((size_t)HC * HC * 2);
    float* alpha = (float*)alloc((size_t)NET * NH * 4);   // edge-major [NET][4]

    const int EB = 256, EG = (NET + EB - 1) / EB;
    const int MT = (NN + 127) / 128;

    // ---- conversions ----
    k_cvt_f16<<<(NN * IND / 4 + 255) / 256, 256, 0, stream>>>(x, xf16, NN * IND / 4);
    k_cvt_wT<<<(HC * IND + 255) / 256, 256, 0, stream>>>(W1, W1T, IND, 8);
    k_cvt_wT<<<(HC * HC + 255) / 256, 256, 0, stream>>>(W2, W2T, HC, 9);

    // ---- CSR build ----
    hipMemsetAsync(deg, 0, (size_t)NN * 4, stream);
    k_deg<<<EG, EB, 0, stream>>>(ei, deg);
    k_scan<<<1, 1024, 0, stream>>>(deg, rowptr, NN);
    hipMemsetAsync(deg, 0, (size_t)NN * 4, stream);
    k_fill<<<EG, EB, 0, stream>>>(ei, rowptr, deg, colsrc);

    // ---- graph offsets ----
    hipMemsetAsync(gcnt, 0, (size_t)NG * 4, stream);
    k_gcnt<<<(NN + 255) / 256, 256, 0, stream>>>(batch, gcnt);
    k_scan<<<1, 1024, 0, stream>>>(gcnt, goff, NG);

    // ================= layer 1 =================
    k_gemm_f16<<<MT * 4, 256, 0, stream>>>(xf16, W1T, asrc1, adst1,
                                           zbf1, as_b, ad_b, NN, IND);
    k_stats<<<(NN + 63) / 64, 256, 0, stream>>>(as_b, ad_b, rowptr, colsrc, alpha, dinv, NN);
    k_gather<<<NN, 128, 0, stream>>>(zbf1, alpha, dinv, rowptr, colsrc, b1,
                                     h2f, h1f16, 1);

    // ================= layer 2 =================
    k_gemm_f16<<<MT * 4, 256, 0, stream>>>(h1f16, W2T, asrc2, adst2,
                                           zbf2, as_b, ad_b, NN, HC);
    k_stats<<<(NN + 63) / 64, 256, 0, stream>>>(as_b, ad_b, rowptr, colsrc, alpha, dinv, NN);
    k_gather<<<NN, 128, 0, stream>>>(zbf2, alpha, dinv, rowptr, colsrc, b2,
                                     h2f, h1f16, 0);

    // ================= pool + classify =================
    k_pool<<<NG, 128, 0, stream>>>(h2f, goff, gcnt, hg);
    k_cls<<<NG, 64, 0, stream>>>(hg, Wc, bc, out);
}